// Round 1
// 562.988 us; speedup vs baseline: 1.0893x; 1.0893x over previous
//
#include <hip/hip_runtime.h>
#include <math.h>

// Problem constants (fixed by setup_inputs)
constexpr int Bc  = 32;     // batch
constexpr int Dc  = 256;    // word feature dim
constexpr int Tc  = 32;     // seq len
constexpr int DHc = 128;    // image feature dim
constexpr int Nc  = 16384;  // H*W = 128*128

typedef _Float16 v8hf __attribute__((ext_vector_type(8)));
typedef _Float16 v2hf __attribute__((ext_vector_type(2)));
typedef float    v4f  __attribute__((ext_vector_type(4)));

// Stage 1: values[b,k,t] = bias[k] + sum_d W[k,d] * wf[b,d,t]   (unchanged)
__global__ __launch_bounds__(256) void values_kernel(
    const float* __restrict__ wf, const float* __restrict__ Wm,
    const float* __restrict__ bias, float* __restrict__ values)
{
    int id = blockIdx.x * 256 + threadIdx.x;    // 131072 total
    int t = id & (Tc - 1);
    int k = (id >> 5) & (DHc - 1);
    int b = id >> 12;
    const float* wrow = Wm + (size_t)k * Dc;
    const float* wfp  = wf + (size_t)b * Dc * Tc + t;
    float acc = bias[k];
    #pragma unroll 8
    for (int d = 0; d < Dc; ++d)
        acc = fmaf(wrow[d], wfp[(size_t)d * Tc], acc);
    values[id] = acc;   // layout [b][k][t] contiguous
}

__device__ __forceinline__ _Float16 pick_half(int u, int sel) {
    unsigned short s = (unsigned short)(sel ? (u >> 16) : u);
    return __builtin_bit_cast(_Float16, s);
}

// Stage 2 (MFMA): per 512-pixel strip of one batch.
// Sᵀ tiles via mfma(Vᵀ, Q) with f16 hi/lo split; in-register masked softmax;
// P relayout via shuffles; attn = (Vh+Vl)·P via mfma.
__global__ __launch_bounds__(256) void attn_kernel(
    const float* __restrict__ img, const float* __restrict__ values,
    const int* __restrict__ mask, float* __restrict__ attn,
    float* __restrict__ coeff)
{
    constexpr int VT_LD = 136;  // k-stride (halves) for Vᵀ tiles, padded: 2-way banks max
    constexpr int VP_LD = 40;   // t-stride (halves) for V tiles, padded
    __shared__ _Float16 VTh[Tc * VT_LD];    //  8.7 KB  Vᵀ hi  [t][k]
    __shared__ _Float16 VTl[Tc * VT_LD];    //  8.7 KB  Vᵀ lo
    __shared__ _Float16 VPh[DHc * VP_LD];   // 10.2 KB  V  hi  [k][t]
    __shared__ _Float16 VPl[DHc * VP_LD];   // 10.2 KB  V  lo
    __shared__ float mneg[Tc];

    const int tid   = threadIdx.x;
    const int b     = blockIdx.x >> 5;
    const int strip = blockIdx.x & 31;      // 32 strips of 512 px per batch

    {   // stage + split V: 4096 elems, 16 per thread
        const float* vb = values + (size_t)b * DHc * Tc;
        #pragma unroll
        for (int i = 0; i < 16; ++i) {
            int idx = tid + 256 * i;
            int k = idx >> 5, t = idx & 31;
            float v = vb[idx];
            _Float16 vh = (_Float16)v;
            _Float16 vl = (_Float16)(v - (float)vh);
            VTh[t * VT_LD + k] = vh;
            VTl[t * VT_LD + k] = vl;
            VPh[k * VP_LD + t] = vh;
            VPl[k * VP_LD + t] = vl;
        }
        if (tid < Tc) mneg[tid] = mask[b * Tc + tid] ? -INFINITY : 0.0f;
    }
    __syncthreads();

    const int lane = tid & 63;
    const int wave = tid >> 6;
    const int c    = lane & 15;   // pixel column within 16-px tile
    const int g    = lane >> 4;   // lane group (k-block / t-row-quad selector)

    // additive mask per lane: C/D row (m-dim) = t = 16*tt + 4*g + r
    float madd[2][4];
    #pragma unroll
    for (int tt = 0; tt < 2; ++tt)
        #pragma unroll
        for (int r = 0; r < 4; ++r)
            madd[tt][r] = mneg[16 * tt + 4 * g + r];

    const float* qbase = img  + ((size_t)b * DHc + 8 * g) * Nc + c;
    float*       abase = attn + ((size_t)b * DHc + 4 * g) * Nc + c;
    float*       cbase = coeff + (size_t)b * Nc * Tc;

    const int ls_lo = c + 32 * (g & 1);   // shuffle source lanes for P relayout
    const int sel   = g >> 1;             // which t-tile half to pick

    for (int it = 0; it < 8; ++it) {
        const int n0 = strip * 512 + (it * 4 + wave) * 16;

        // ---- load Q columns (B-operand: lane = pixel c, k = ks*32+8g+j), split hi/lo ----
        float q[4][8];
        const float* qp = qbase + n0;
        #pragma unroll
        for (int ks = 0; ks < 4; ++ks)
            #pragma unroll
            for (int j = 0; j < 8; ++j)
                q[ks][j] = qp[(size_t)(ks * 32 + j) * Nc];

        v8hf Qh[4], Ql[4];
        #pragma unroll
        for (int ks = 0; ks < 4; ++ks)
            #pragma unroll
            for (int j = 0; j < 8; ++j) {
                _Float16 h = (_Float16)q[ks][j];
                Qh[ks][j] = h;
                Ql[ks][j] = (_Float16)(q[ks][j] - (float)h);
            }

        // ---- Sᵀ = Vᵀ·Q : 2 t-tiles × 4 k-steps × 3 split terms ----
        v4f Sh[2], Sl[2];
        #pragma unroll
        for (int tt = 0; tt < 2; ++tt) {
            Sh[tt] = (v4f){0.f, 0.f, 0.f, 0.f};
            Sl[tt] = (v4f){0.f, 0.f, 0.f, 0.f};
        }
        #pragma unroll
        for (int tt = 0; tt < 2; ++tt) {
            const int rowbase = (16 * tt + c) * VT_LD + 8 * g;
            #pragma unroll
            for (int ks = 0; ks < 4; ++ks) {
                v8hf va = *(const v8hf*)&VTh[rowbase + ks * 32];
                v8hf vl = *(const v8hf*)&VTl[rowbase + ks * 32];
                Sh[tt] = __builtin_amdgcn_mfma_f32_16x16x32_f16(va, Qh[ks], Sh[tt], 0, 0, 0);
                Sl[tt] = __builtin_amdgcn_mfma_f32_16x16x32_f16(va, Ql[ks], Sl[tt], 0, 0, 0);
                Sl[tt] = __builtin_amdgcn_mfma_f32_16x16x32_f16(vl, Qh[ks], Sl[tt], 0, 0, 0);
            }
        }

        // ---- masked softmax over t (8 values in-lane + 4-lane shfl reduce) ----
        float p0[4], p1[4];
        float m = -INFINITY;
        #pragma unroll
        for (int r = 0; r < 4; ++r) {
            p0[r] = Sh[0][r] + Sl[0][r] + madd[0][r];
            p1[r] = Sh[1][r] + Sl[1][r] + madd[1][r];
            m = fmaxf(m, fmaxf(p0[r], p1[r]));
        }
        m = fmaxf(m, __shfl_xor(m, 16));
        m = fmaxf(m, __shfl_xor(m, 32));
        float sum = 0.0f;
        #pragma unroll
        for (int r = 0; r < 4; ++r) {
            p0[r] = __expf(p0[r] - m); sum += p0[r];
            p1[r] = __expf(p1[r] - m); sum += p1[r];
        }
        sum += __shfl_xor(sum, 16);
        sum += __shfl_xor(sum, 32);
        const float inv = 1.0f / sum;
        #pragma unroll
        for (int r = 0; r < 4; ++r) { p0[r] *= inv; p1[r] *= inv; }

        // ---- coefficients [B,N,T]: lane writes t=4g..4g+3 and +16 of pixel n0+c ----
        float* cp = cbase + (size_t)(n0 + c) * Tc + 4 * g;
        *(float4*)cp        = make_float4(p0[0], p0[1], p0[2], p0[3]);
        *(float4*)(cp + 16) = make_float4(p1[0], p1[1], p1[2], p1[3]);

        // ---- relayout P into PV B-fragment: need t = 8g+j for pixel c ----
        v8hf Pb;
        #pragma unroll
        for (int r = 0; r < 4; ++r) {
            v2hf h2; h2[0] = (_Float16)p0[r]; h2[1] = (_Float16)p1[r];
            int u   = __builtin_bit_cast(int, h2);
            int ulo = __shfl(u, ls_lo);
            int uhi = __shfl(u, ls_lo + 16);
            Pb[r]     = pick_half(ulo, sel);
            Pb[4 + r] = pick_half(uhi, sel);
        }

        // ---- attn = V·P : 8 k-tiles, K=32 covers all t; hi+lo terms ----
        #pragma unroll
        for (int mt = 0; mt < 8; ++mt) {
            const int vrow = (16 * mt + c) * VP_LD + 8 * g;
            v8hf va  = *(const v8hf*)&VPh[vrow];
            v8hf vb2 = *(const v8hf*)&VPl[vrow];
            v4f o = (v4f){0.f, 0.f, 0.f, 0.f};
            o = __builtin_amdgcn_mfma_f32_16x16x32_f16(va,  Pb, o, 0, 0, 0);
            o = __builtin_amdgcn_mfma_f32_16x16x32_f16(vb2, Pb, o, 0, 0, 0);
            float* ap = abase + (size_t)(16 * mt) * Nc + n0;
            #pragma unroll
            for (int r = 0; r < 4; ++r)
                ap[(size_t)r * Nc] = o[r];   // row k=16mt+4g+r, col n0+c
        }
    }
}

extern "C" void kernel_launch(void* const* d_in, const int* in_sizes, int n_in,
                              void* d_out, int out_size, void* d_ws, size_t ws_size,
                              hipStream_t stream)
{
    const float* wf   = (const float*)d_in[0];  // [B,D,T]
    const float* img  = (const float*)d_in[1];  // [B,Dh,H,W]
    const int*   msk  = (const int*)d_in[2];    // [B,T]
    const float* Wm   = (const float*)d_in[3];  // [Dh,D]
    const float* bias = (const float*)d_in[4];  // [Dh]

    float* attn  = (float*)d_out;                        // [B,Dh,N]
    float* coeff = attn + (size_t)Bc * DHc * Nc;         // [B,N,T]
    float* vals  = (float*)d_ws;                         // [B,Dh,T] scratch (512 KB)

    values_kernel<<<(Bc * DHc * Tc) / 256, 256, 0, stream>>>(wf, Wm, bias, vals);
    attn_kernel<<<Bc * 32, 256, 0, stream>>>(img, vals, msk, attn, coeff);
}